// Round 18
// baseline (808.583 us; speedup 1.0000x reference)
//
#include <hip/hip_runtime.h>

typedef _Float16 f16;
typedef __attribute__((ext_vector_type(8))) _Float16 f16x8;
typedef __attribute__((ext_vector_type(4))) _Float16 f16x4;
typedef __attribute__((ext_vector_type(4))) float f32x4;

#define TT 4
#define BB 16
#define CC 384

// epilogue transpose-buffer swizzle (R11-proven: conflicts -> 0)
#define SWZ(R) ((((R) & 31)) ^ ((((R) & 4)) << 2))

// ---------- LIF step helpers (mirror reference op order, no fma contraction) ----------
__device__ __forceinline__ float lif_soft(float x, float& v) {
  v = __fadd_rn(v, __fmul_rn(__fsub_rn(x, v), 0.5f));
  float s = (__fsub_rn(v, 1.0f) >= 0.0f) ? 1.0f : 0.0f;
  v = __fsub_rn(v, s);
  return s;
}
__device__ __forceinline__ float lif_hard(float x, float& v, float vth) {
  v = __fadd_rn(v, __fmul_rn(__fsub_rn(x, v), 0.5f));
  float s = (__fsub_rn(v, vth) >= 0.0f) ? 1.0f : 0.0f;
  if (s != 0.0f) v = 0.0f;
  return s;
}

// ---------- merged prep: 4 weight splits + BN folding in one launch (R13-proven) ----------
__global__ __launch_bounds__(256) void k_prep_all(const float* __restrict__ w1, const float* __restrict__ pw,
    const float* __restrict__ q1, const float* __restrict__ qp,
    f16* __restrict__ w1a, f16* __restrict__ w1b, f16* __restrict__ pwa, f16* __restrict__ pwb,
    f16* __restrict__ q1a, f16* __restrict__ q1b, f16* __restrict__ qpa, f16* __restrict__ qpb,
    const float* __restrict__ bn1, const float* __restrict__ bn2, const float* __restrict__ qkv,
    const float* __restrict__ rbn1, const float* __restrict__ rbn2, const float* __restrict__ proj,
    float* __restrict__ par) {
  int bid = blockIdx.x;
  if (bid < 2880) {
    int i = bid*256 + threadIdx.x;
    const float* s; f16 *da, *db; int idx;
    if (i < 147456)      { s = w1; da = w1a; db = w1b; idx = i; }
    else if (i < 442368) { s = pw; da = pwa; db = pwb; idx = i - 147456; }
    else if (i < 589824) { s = q1; da = q1a; db = q1b; idx = i - 442368; }
    else                 { s = qp; da = qpa; db = qpb; idx = i - 589824; }
    float x = s[idx];
    f16 a = (f16)x;
    da[idx] = a;
    db[idx] = (f16)((x - (float)a) * 2048.0f);
    return;
  }
  int c = (bid - 2880)*256 + threadIdx.x;   // 0..767
  float* s1 = par;          float* o1 = par + 384;
  float* sA = par + 768;    float* oA = par + 1536;
  float* s2 = par + 2304;   float* o2 = par + 2688;
  float* sB = par + 3072;   float* oB = par + 3456;
  if (c < 384) {
    double a = (double)bn1[c] / sqrt((double)bn1[3*384+c] + 1e-5);
    s1[c] = (float)a;
    o1[c] = (float)((double)bn1[384+c] - (double)bn1[2*384+c]*a);
    double a2 = (double)rbn1[c] / sqrt((double)rbn1[3*384+c] + 1e-5);
    s2[c] = (float)a2;
    o2[c] = (float)((double)rbn1[384+c] - (double)rbn1[2*384+c]*a2);
    double a3 = (double)rbn2[c] / sqrt((double)rbn2[3*384+c] + 1e-5);
    double b3 = (double)rbn2[384+c] - (double)rbn2[2*384+c]*a3;
    double a4 = (double)proj[c] / sqrt((double)proj[3*384+c] + 1e-5);
    double b4 = (double)proj[384+c] - (double)proj[2*384+c]*a4;
    sB[c] = (float)(a3*a4);
    oB[c] = (float)(b3*a4 + b4);
  }
  if (c < 768) {
    double a5 = (double)bn2[c] / sqrt((double)bn2[3*768+c] + 1e-5);
    double b5 = (double)bn2[768+c] - (double)bn2[2*768+c]*a5;
    double a6 = (double)qkv[c] / sqrt((double)qkv[3*768+c] + 1e-5);
    double b6 = (double)qkv[768+c] - (double)qkv[2*768+c]*a6;
    sA[c] = (float)(a5*a6);
    oA[c] = (float)(b5*a6 + b6);
  }
}

// ---------- input LIF: NCHW fp32 -> NHWC f16 spikes (LDS transpose) ----------
__global__ __launch_bounds__(256) void k_lif_in(const float* __restrict__ x, f16* __restrict__ xs) {
  __shared__ float tile[64][65];   // [c][p]
  const int p0 = blockIdx.x * 64, c0 = blockIdx.y * 64, b = blockIdx.z;
  const int l = threadIdx.x & 63, q = threadIdx.x >> 6;
  float v[16];
  #pragma unroll
  for (int j = 0; j < 16; ++j) v[j] = 0.0f;
  for (int t = 0; t < TT; ++t) {
    __syncthreads();
    #pragma unroll
    for (int j = 0; j < 16; ++j) {
      int ci = q + j*4;
      tile[ci][l] = x[(((size_t)(t*BB + b)*CC + c0 + ci) << 10) + p0 + l];
    }
    __syncthreads();
    #pragma unroll
    for (int j = 0; j < 16; ++j) {
      int pi = q + j*4;
      float s = lif_hard(tile[l][pi], v[j], 1.0f);
      xs[((size_t)(t*BB + b)*1024 + p0 + pi)*CC + c0 + l] = (f16)s;
    }
  }
}

// fragment read offset helper (row in [0,128), fq selects 16B k-slot; returns BYTES)
__device__ __forceinline__ int fragoff(int row, int fq) {
  return row*64 + ((fq*16) ^ (((row >> 1) & 3) << 4));
}

#define GLL(srcP, dstP) __builtin_amdgcn_global_load_lds( \
    (const __attribute__((address_space(1))) void*)(srcP), \
    (__attribute__((address_space(3))) void*)(dstP), 16, 0, 0)

// ---------- NP2 GEMM (gemm1/gemm3): hoisted pointers, 3 blocks/CU ----------
template<int GATE>
__global__ __launch_bounds__(256, 3) void k_gemmA(const f16* __restrict__ X1,
    const f16* __restrict__ Wa, const f16* __restrict__ Wb,
    const float* __restrict__ scale, const float* __restrict__ bias,
    float* __restrict__ out0, const f16* __restrict__ gatep) {
  __shared__ __align__(16) f16 lds[2*3*4096];       // 48 KB
  char* lbase = (char*)lds;
  const int gx = gridDim.x;
  const int bid = blockIdx.y * gx + blockIdx.x;
  const int chunk = (gx * gridDim.y) >> 3;
  const int nb = (bid & 7) * chunk + (bid >> 3);
  const int o0 = (nb % gx) * 128;
  const int m0 = (nb / gx) * 128;
  const int lane = threadIdx.x & 63, wid = threadIdx.x >> 6;
  const int wr = wid >> 1, wc = wid & 1;
  const int fr = lane & 15, fq = lane >> 4;
  f32x4 acc_h[4][4], acc_l[4][4];
  #pragma unroll
  for (int i = 0; i < 4; ++i)
    #pragma unroll
    for (int j = 0; j < 4; ++j) { acc_h[i][j] = (f32x4){0,0,0,0}; acc_l[i][j] = (f32x4){0,0,0,0}; }

  const f16* gp; int i0, nst, arr, row0;
  if (wid == 0)      { gp = X1; arr = 0; i0 = 0; nst = 4; row0 = m0; }
  else if (wid == 1) { gp = X1; arr = 0; i0 = 4; nst = 4; row0 = m0; }
  else if (wid == 2) { gp = Wa; arr = 1; i0 = 0; nst = 8; row0 = o0; }
  else               { gp = Wb; arr = 2; i0 = 0; nst = 8; row0 = o0; }
  const char* srcp[8]; int dsto[8];
  #pragma unroll
  for (int j = 0; j < 8; ++j) {
    int i = i0 + (j < nst ? j : 0);
    int loff = i*1024 + lane*16;
    int row = loff >> 6, col = loff & 63;
    int scol = col ^ (((row >> 1) & 3) << 4);
    srcp[j] = (const char*)gp + (size_t)(row0 + row)*768 + scol;
    dsto[j] = arr*8192 + i*1024;
  }
  int offA[4], offB1[4], offB2[4];
  #pragma unroll
  for (int mi = 0; mi < 4; ++mi) offA[mi] = fragoff(wr*64 + mi*16 + fr, fq);
  #pragma unroll
  for (int oi = 0; oi < 4; ++oi) {
    int o = fragoff(wc*64 + oi*16 + fr, fq);
    offB1[oi] = 8192 + o;
    offB2[oi] = 16384 + o;
  }

  const char* gb = nullptr; f16x8 gcur{}, gnxt{};
  if constexpr (GATE) {
    gb = (const char*)gatep + (size_t)(m0 >> 10)*768 + fq*16;
    gcur = *(const f16x8*)gb; gb += 64;
  }

#define ISSUE_A(BUF) { _Pragma("unroll") for (int j = 0; j < 8; ++j) if (j < nst) { \
    GLL(srcp[j], lbase + (BUF) + dsto[j]); srcp[j] += 64; } }
#define COMPUTE_A(BUF) { f16x8 a1[4], b1[4], b2[4]; \
    _Pragma("unroll") for (int mi = 0; mi < 4; ++mi) { \
      a1[mi] = *(const f16x8*)(lbase + (BUF) + offA[mi]); \
      if constexpr (GATE) a1[mi] = a1[mi] * gcur; } \
    _Pragma("unroll") for (int oi = 0; oi < 4; ++oi) { \
      b1[oi] = *(const f16x8*)(lbase + (BUF) + offB1[oi]); \
      b2[oi] = *(const f16x8*)(lbase + (BUF) + offB2[oi]); } \
    _Pragma("unroll") for (int mi = 0; mi < 4; ++mi) \
      _Pragma("unroll") for (int oi = 0; oi < 4; ++oi) { \
        acc_h[mi][oi] = __builtin_amdgcn_mfma_f32_16x16x32_f16(a1[mi], b1[oi], acc_h[mi][oi], 0, 0, 0); \
        acc_l[mi][oi] = __builtin_amdgcn_mfma_f32_16x16x32_f16(a1[mi], b2[oi], acc_l[mi][oi], 0, 0, 0); } }

  ISSUE_A(0);
  __syncthreads();
  #pragma unroll 1
  for (int it2 = 0; it2 < 6; ++it2) {
    ISSUE_A(24576);
    if constexpr (GATE) { gnxt = *(const f16x8*)gb; gb += 64; }
    COMPUTE_A(0);
    if constexpr (GATE) gcur = gnxt;
    __syncthreads();
    if (it2 < 5) {
      ISSUE_A(0);
      if constexpr (GATE) { gnxt = *(const f16x8*)gb; gb += 64; }
    }
    COMPUTE_A(24576);
    if constexpr (GATE) gcur = gnxt;
    __syncthreads();
  }
#undef ISSUE_A
#undef COMPUTE_A

  #pragma unroll
  for (int oi = 0; oi < 4; ++oi) {
    int o = o0 + wc*64 + oi*16 + fr;
    float sc = scale[o], bi = bias[o];
    #pragma unroll
    for (int mi = 0; mi < 4; ++mi) {
      f32x4 h = acc_h[mi][oi], lo2 = acc_l[mi][oi];
      #pragma unroll
      for (int r = 0; r < 4; ++r) {
        int m = m0 + wr*64 + mi*16 + fq*4 + r;
        float y = fmaf(0.00048828125f, lo2[r], h[r]);
        out0[(size_t)m*384 + o] = fmaf(y, sc, bi);
      }
    }
  }
}

// ---------- NP3 GEMM (qkv/proj): hoisted staging pointers, X2 LDS-staged ----------
// EPI=1: qkv fused LIF epilogue; EPI=2: proj fused output LIF, NCHW store.
template<int EPI>
__global__ __launch_bounds__(256, 2) void k_gemmB(const f16* __restrict__ X1, const f16* __restrict__ X2,
    const f16* __restrict__ Wa, const f16* __restrict__ Wb,
    const float* __restrict__ scale, const float* __restrict__ bias,
    float* __restrict__ outF, const float* __restrict__ gscale,
    f16* __restrict__ sOut, f16* __restrict__ part) {
  __shared__ __align__(16) f16 lds[2*4*4096];       // 64 KB (4 arrays x 8KB x 2 buf)
  char* lbase = (char*)lds;
  const int gx = gridDim.x;
  const int bid = blockIdx.y * gx + blockIdx.x;
  const int chunk = (gx * gridDim.y) >> 3;
  const int nb = (bid & 7) * chunk + (bid >> 3);
  const int o0 = (nb % gx) * 128;
  const int mb = nb / gx;
  const int b_ = mb >> 5, p0 = (mb & 31) << 5;      // t-grouped m-block decode
  const int lane = threadIdx.x & 63, wid = threadIdx.x >> 6;
  const int wr = wid >> 1, wc = wid & 1;
  const int fr = lane & 15, fq = lane >> 4;
  f32x4 acc_h[4][4], acc_l[4][4];
  #pragma unroll
  for (int i = 0; i < 4; ++i)
    #pragma unroll
    for (int j = 0; j < 4; ++j) { acc_h[i][j] = (f32x4){0,0,0,0}; acc_l[i][j] = (f32x4){0,0,0,0}; }

  // hoisted staging pointers: wave wid stages array wid (X1,X2,Wa,Wb), 8 insts each
  const f16* gp = (wid == 0) ? X1 : (wid == 1) ? X2 : (wid == 2) ? Wa : Wb;
  const bool isX = (wid <= 1);
  const char* srcp[8]; int dsto[8];
  #pragma unroll
  for (int i = 0; i < 8; ++i) {
    int loff = i*1024 + lane*16;              // BYTE offset within 8 KB tile
    int row = loff >> 6, col = loff & 63;
    int scol = col ^ (((row >> 1) & 3) << 4);
    int gm = isX ? (((row >> 5) << 14) + (b_ << 10) + p0 + (row & 31)) : (o0 + row);
    srcp[i] = (const char*)gp + (size_t)gm*768 + scol;
    dsto[i] = wid*8192 + i*1024;
  }
  int offA1[4], offA2[4], offB1[4], offB2[4];
  #pragma unroll
  for (int mi = 0; mi < 4; ++mi) {
    int o = fragoff(wr*64 + mi*16 + fr, fq);
    offA1[mi] = o;
    offA2[mi] = 8192 + o;
  }
  #pragma unroll
  for (int oi = 0; oi < 4; ++oi) {
    int o = fragoff(wc*64 + oi*16 + fr, fq);
    offB1[oi] = 16384 + o;
    offB2[oi] = 24576 + o;
  }

#define ISSUE_B(BUF) { _Pragma("unroll") for (int i = 0; i < 8; ++i) { \
    GLL(srcp[i], lbase + (BUF) + dsto[i]); srcp[i] += 64; } }
#define COMPUTE_B(BUF) { f16x8 a1[4], a2[4], b1[4], b2[4]; \
    _Pragma("unroll") for (int mi = 0; mi < 4; ++mi) { \
      a1[mi] = *(const f16x8*)(lbase + (BUF) + offA1[mi]); \
      a2[mi] = *(const f16x8*)(lbase + (BUF) + offA2[mi]); } \
    _Pragma("unroll") for (int oi = 0; oi < 4; ++oi) { \
      b1[oi] = *(const f16x8*)(lbase + (BUF) + offB1[oi]); \
      b2[oi] = *(const f16x8*)(lbase + (BUF) + offB2[oi]); } \
    _Pragma("unroll") for (int mi = 0; mi < 4; ++mi) \
      _Pragma("unroll") for (int oi = 0; oi < 4; ++oi) { \
        acc_h[mi][oi] = __builtin_amdgcn_mfma_f32_16x16x32_f16(a1[mi], b1[oi], acc_h[mi][oi], 0, 0, 0); \
        acc_l[mi][oi] = __builtin_amdgcn_mfma_f32_16x16x32_f16(a1[mi], b2[oi], acc_l[mi][oi], 0, 0, 0); \
        acc_l[mi][oi] = __builtin_amdgcn_mfma_f32_16x16x32_f16(a2[mi], b1[oi], acc_l[mi][oi], 0, 0, 0); } }

  ISSUE_B(0);
  __syncthreads();
  #pragma unroll 1
  for (int it2 = 0; it2 < 6; ++it2) {
    ISSUE_B(32768);
    COMPUTE_B(0);
    __syncthreads();
    if (it2 < 5) ISSUE_B(0);
    COMPUTE_B(32768);
    __syncthreads();
  }
#undef ISSUE_B
#undef COMPUTE_B

  // fused epilogue: BN -> in-LDS transpose (SWZ cols) -> LIF over t
  float* T = (float*)lds;
  #pragma unroll
  for (int oi = 0; oi < 4; ++oi) {
    int ol = wc*64 + oi*16 + fr;
    float sc = scale[o0 + ol], bi = bias[o0 + ol];
    #pragma unroll
    for (int mi = 0; mi < 4; ++mi) {
      f32x4 h = acc_h[mi][oi], lo2 = acc_l[mi][oi];
      #pragma unroll
      for (int r = 0; r < 4; ++r) {
        int R = wr*64 + mi*16 + fq*4 + r;
        float y = fmaf(0.00048828125f, lo2[r], h[r]);
        T[R*128 + (ol ^ SWZ(R))] = fmaf(y, sc, bi);
      }
    }
  }
  __syncthreads();
  const int tid = threadIdx.x;
  if constexpr (EPI == 1) {
    const int oc = tid & 127, ph = tid >> 7;
    if (o0 >= 384) {
      const int ocg = (o0 - 384) + oc;
      #pragma unroll
      for (int i = 0; i < 16; ++i) {
        int p = ph*16 + i;
        float v = 0.0f;
        #pragma unroll
        for (int t = 0; t < TT; ++t) {
          int R = t*32 + p;
          float s = lif_soft(T[R*128 + (oc ^ SWZ(R))], v);
          sOut[((size_t)((t*16 + b_)*1024 + p0 + p))*384 + ocg] = (f16)s;
        }
      }
    } else {
      float ps4[4] = {0,0,0,0};
      for (int i = 0; i < 16; ++i) {
        int p = ph*16 + i;
        float v = 0.0f;
        #pragma unroll
        for (int t = 0; t < TT; ++t) {
          int R = t*32 + p;
          ps4[t] += lif_soft(T[R*128 + (oc ^ SWZ(R))], v);
        }
      }
      int slice = (p0 >> 4) + ph;
      #pragma unroll
      for (int t = 0; t < TT; ++t)
        part[(((size_t)slice*4 + t)*16 + b_)*384 + o0 + oc] = (f16)ps4[t];
    }
  } else {
    const int p = tid & 31, cg = tid >> 5;
    const float gsc = gscale[0];
    #pragma unroll
    for (int j = 0; j < 16; ++j) {
      int c = cg*16 + j;
      float v = 0.0f;
      #pragma unroll
      for (int t = 0; t < TT; ++t) {
        int R = t*32 + p;
        float s = lif_soft(T[R*128 + (c ^ SWZ(R))], v) * gsc;
        outF[(((size_t)(t*16 + b_)*384) + o0 + c)*1024 + p0 + p] = s;
      }
    }
  }
}

// ---------- depthwise 3x3, NHWC, float4 channel-quads, fp32 in -> split-f16 out ----------
__global__ __launch_bounds__(256) void k_dw(const float* __restrict__ in, const float* __restrict__ wd,
                                            const float* __restrict__ pv,
                                            f16* __restrict__ outA, f16* __restrict__ outB) {
  const int ct = blockIdx.x, h = blockIdx.y, n = blockIdx.z;
  const int cq = threadIdx.x & 15, wg = threadIdx.x >> 4;
  const int c0 = ct*64 + cq*4;
  const int w0 = wg*2;
  float w9[9][4];
  #pragma unroll
  for (int j = 0; j < 4; ++j)
    #pragma unroll
    for (int k = 0; k < 9; ++k) w9[k][j] = wd[(c0 + j)*9 + k];
  const float4 pv4 = *(const float4*)&pv[c0];
  const float* base = in + (size_t)n*1024*CC;
  float4 col[3][4];
  #pragma unroll
  for (int r = 0; r < 3; ++r)
    #pragma unroll
    for (int j = 0; j < 4; ++j) {
      int hh = h - 1 + r, ww = w0 - 1 + j;
      col[r][j] = ((unsigned)hh < 32u && (unsigned)ww < 32u)
                  ? *(const float4*)&base[(size_t)(hh*32 + ww)*CC + c0] : pv4;
    }
  #pragma unroll
  for (int wi = 0; wi < 2; ++wi) {
    float acc[4] = {0.f, 0.f, 0.f, 0.f};
    #pragma unroll
    for (int dh = 0; dh < 3; ++dh)
      #pragma unroll
      for (int dwj = 0; dwj < 3; ++dwj) {
        float4 vv = col[dh][wi + dwj];
        const float* wk = w9[dh*3 + dwj];
        acc[0] = fmaf(wk[0], vv.x, acc[0]);
        acc[1] = fmaf(wk[1], vv.y, acc[1]);
        acc[2] = fmaf(wk[2], vv.z, acc[2]);
        acc[3] = fmaf(wk[3], vv.w, acc[3]);
      }
    f16x4 a4, b4;
    #pragma unroll
    for (int j = 0; j < 4; ++j) {
      f16 a = (f16)acc[j];
      a4[j] = a;
      b4[j] = (f16)((acc[j] - (float)a) * 2048.0f);
    }
    size_t off = ((size_t)n*1024 + h*32 + w0 + wi)*CC + c0;
    *(f16x4*)&outA[off] = a4;
    *(f16x4*)&outB[off] = b4;
  }
}

// ---------- gate: combine 64 partial half-slices + LIF(hard 0.5) -> f16 gate ----------
__global__ __launch_bounds__(256) void k_gate(const f16* __restrict__ partial, f16* __restrict__ gate16) {
  int g = blockIdx.x*256 + threadIdx.x;   // 6144 = 16*384
  int b = g / CC, c = g % CC;
  float sums[4];
  #pragma unroll
  for (int t = 0; t < TT; ++t) {
    float s = 0.0f;
    for (int ps = 0; ps < 64; ++ps) s += (float)partial[(((size_t)ps*4 + t)*BB + b)*CC + c];
    sums[t] = s;
  }
  float v = 0.0f;
  #pragma unroll
  for (int t = 0; t < TT; ++t)
    gate16[((size_t)(t*BB + b))*CC + c] = (f16)lif_hard(sums[t], v, 0.5f);
}

extern "C" void kernel_launch(void* const* d_in, const int* in_sizes, int n_in,
                              void* d_out, int out_size, void* d_ws, size_t ws_size,
                              hipStream_t stream) {
  const float* x      = (const float*)d_in[0];
  const float* r1_w1  = (const float*)d_in[1];
  const float* r1_bn1 = (const float*)d_in[2];
  const float* r1_dw  = (const float*)d_in[3];
  const float* r1_pw  = (const float*)d_in[4];
  const float* r1_bn2 = (const float*)d_in[5];
  const float* qkv_bn = (const float*)d_in[6];
  const float* r2_w1  = (const float*)d_in[7];
  const float* r2_bn1 = (const float*)d_in[8];
  const float* r2_dw  = (const float*)d_in[9];
  const float* r2_pw  = (const float*)d_in[10];
  const float* r2_bn2 = (const float*)d_in[11];
  const float* proj_bn= (const float*)d_in[12];
  const float* scale  = (const float*)d_in[13];

  float* ws = (float*)d_ws;
  const size_t SEG = 12582912;              // 50.3 MB in floats
  float* W0f = ws;                          // f16 region: xs -> s16
  float* W1  = ws + SEG;                    // fp32: t1 -> t2
  float* W2f = ws + 3*SEG;                  // f16 region: p1a -> p2a
  float* W3f = ws + 4*SEG;                  // f16 region: p1b -> p2b
  f16* xs  = (f16*)W0f;
  f16* s16 = (f16*)W0f;
  float* t1 = W1;
  float* t2 = W1;
  f16* p1a = (f16*)W2f;
  f16* p2a = (f16*)W2f;
  f16* p1b = (f16*)W3f;
  f16* p2b = (f16*)W3f;

  f16* wsp = (f16*)(ws + 6*SEG);            // param region
  f16* w1a = wsp,              *w1b = wsp + 147456;
  f16* pwa = wsp + 294912,     *pwb = wsp + 589824;
  f16* q1a = wsp + 884736,     *q1b = wsp + 1032192;
  f16* qpa = wsp + 1179648,    *qpb = wsp + 1327104;
  f16* partial = wsp + 1474560;             // 64*4*16*384 f16
  f16* gate16  = wsp + 3047424;             // 64*384 f16
  float* par = (float*)(wsp + 3072000);     // 3840 floats
  float* s1 = par,        *o1 = par + 384;
  float* sA = par + 768,  *oA = par + 1536;
  float* s2 = par + 2304, *o2 = par + 2688;
  float* sB = par + 3072, *oB = par + 3456;

  k_prep_all<<<2883, 256, 0, stream>>>(r1_w1, r1_pw, r2_w1, r2_pw,
                                       w1a, w1b, pwa, pwb, q1a, q1b, qpa, qpb,
                                       r1_bn1, r1_bn2, qkv_bn, r2_bn1, r2_bn2, proj_bn, par);
  k_lif_in<<<dim3(16, 6, 16), 256, 0, stream>>>(x, xs);
  // repconv1
  k_gemmA<0><<<dim3(3, 512), 256, 0, stream>>>(xs, w1a, w1b, s1, o1, t1, nullptr);
  k_dw<<<dim3(6, 32, 64), 256, 0, stream>>>(t1, r1_dw, o1, p1a, p1b);
  // qkv GEMM with fused LIF epilogue: qk -> partial sums, v -> spikes
  k_gemmB<1><<<dim3(6, 512), 256, 0, stream>>>(p1a, p1b, pwa, pwb, sA, oA,
                                               nullptr, nullptr, s16, partial);
  k_gate<<<24, 256, 0, stream>>>(partial, gate16);
  // repconv2 (gate applied inline on A-frags)
  k_gemmA<1><<<dim3(3, 512), 256, 0, stream>>>(s16, q1a, q1b, s2, o2, t2, gate16);
  k_dw<<<dim3(6, 32, 64), 256, 0, stream>>>(t2, r2_dw, o2, p2a, p2b);
  // proj GEMM with fused output LIF, direct NCHW write
  k_gemmB<2><<<dim3(3, 512), 256, 0, stream>>>(p2a, p2b, qpa, qpb, sB, oB,
                                               (float*)d_out, scale, nullptr, nullptr);
}

// Round 19
// 490.449 us; speedup vs baseline: 1.6487x; 1.6487x over previous
//
#include <hip/hip_runtime.h>

typedef _Float16 f16;
typedef __attribute__((ext_vector_type(8))) _Float16 f16x8;
typedef __attribute__((ext_vector_type(4))) _Float16 f16x4;
typedef __attribute__((ext_vector_type(4))) float f32x4;

#define TT 4
#define BB 16
#define CC 384

// epilogue transpose-buffer swizzle (R11-proven: conflicts -> 0)
#define SWZ(R) ((((R) & 31)) ^ ((((R) & 4)) << 2))

// ---------- LIF step helpers (mirror reference op order, no fma contraction) ----------
__device__ __forceinline__ float lif_soft(float x, float& v) {
  v = __fadd_rn(v, __fmul_rn(__fsub_rn(x, v), 0.5f));
  float s = (__fsub_rn(v, 1.0f) >= 0.0f) ? 1.0f : 0.0f;
  v = __fsub_rn(v, s);
  return s;
}
__device__ __forceinline__ float lif_hard(float x, float& v, float vth) {
  v = __fadd_rn(v, __fmul_rn(__fsub_rn(x, v), 0.5f));
  float s = (__fsub_rn(v, vth) >= 0.0f) ? 1.0f : 0.0f;
  if (s != 0.0f) v = 0.0f;
  return s;
}

// ---------- merged prep: 4 weight splits + BN folding in one launch (R13-proven) ----------
__global__ __launch_bounds__(256) void k_prep_all(const float* __restrict__ w1, const float* __restrict__ pw,
    const float* __restrict__ q1, const float* __restrict__ qp,
    f16* __restrict__ w1a, f16* __restrict__ w1b, f16* __restrict__ pwa, f16* __restrict__ pwb,
    f16* __restrict__ q1a, f16* __restrict__ q1b, f16* __restrict__ qpa, f16* __restrict__ qpb,
    const float* __restrict__ bn1, const float* __restrict__ bn2, const float* __restrict__ qkv,
    const float* __restrict__ rbn1, const float* __restrict__ rbn2, const float* __restrict__ proj,
    float* __restrict__ par) {
  int bid = blockIdx.x;
  if (bid < 2880) {
    int i = bid*256 + threadIdx.x;
    const float* s; f16 *da, *db; int idx;
    if (i < 147456)      { s = w1; da = w1a; db = w1b; idx = i; }
    else if (i < 442368) { s = pw; da = pwa; db = pwb; idx = i - 147456; }
    else if (i < 589824) { s = q1; da = q1a; db = q1b; idx = i - 442368; }
    else                 { s = qp; da = qpa; db = qpb; idx = i - 589824; }
    float x = s[idx];
    f16 a = (f16)x;
    da[idx] = a;
    db[idx] = (f16)((x - (float)a) * 2048.0f);
    return;
  }
  int c = (bid - 2880)*256 + threadIdx.x;   // 0..767
  float* s1 = par;          float* o1 = par + 384;
  float* sA = par + 768;    float* oA = par + 1536;
  float* s2 = par + 2304;   float* o2 = par + 2688;
  float* sB = par + 3072;   float* oB = par + 3456;
  if (c < 384) {
    double a = (double)bn1[c] / sqrt((double)bn1[3*384+c] + 1e-5);
    s1[c] = (float)a;
    o1[c] = (float)((double)bn1[384+c] - (double)bn1[2*384+c]*a);
    double a2 = (double)rbn1[c] / sqrt((double)rbn1[3*384+c] + 1e-5);
    s2[c] = (float)a2;
    o2[c] = (float)((double)rbn1[384+c] - (double)rbn1[2*384+c]*a2);
    double a3 = (double)rbn2[c] / sqrt((double)rbn2[3*384+c] + 1e-5);
    double b3 = (double)rbn2[384+c] - (double)rbn2[2*384+c]*a3;
    double a4 = (double)proj[c] / sqrt((double)proj[3*384+c] + 1e-5);
    double b4 = (double)proj[384+c] - (double)proj[2*384+c]*a4;
    sB[c] = (float)(a3*a4);
    oB[c] = (float)(b3*a4 + b4);
  }
  if (c < 768) {
    double a5 = (double)bn2[c] / sqrt((double)bn2[3*768+c] + 1e-5);
    double b5 = (double)bn2[768+c] - (double)bn2[2*768+c]*a5;
    double a6 = (double)qkv[c] / sqrt((double)qkv[3*768+c] + 1e-5);
    double b6 = (double)qkv[768+c] - (double)qkv[2*768+c]*a6;
    sA[c] = (float)(a5*a6);
    oA[c] = (float)(b5*a6 + b6);
  }
}

// ---------- input LIF: NCHW fp32 -> NHWC f16 spikes (LDS transpose) ----------
__global__ __launch_bounds__(256) void k_lif_in(const float* __restrict__ x, f16* __restrict__ xs) {
  __shared__ float tile[64][65];   // [c][p]
  const int p0 = blockIdx.x * 64, c0 = blockIdx.y * 64, b = blockIdx.z;
  const int l = threadIdx.x & 63, q = threadIdx.x >> 6;
  float v[16];
  #pragma unroll
  for (int j = 0; j < 16; ++j) v[j] = 0.0f;
  for (int t = 0; t < TT; ++t) {
    __syncthreads();
    #pragma unroll
    for (int j = 0; j < 16; ++j) {
      int ci = q + j*4;
      tile[ci][l] = x[(((size_t)(t*BB + b)*CC + c0 + ci) << 10) + p0 + l];
    }
    __syncthreads();
    #pragma unroll
    for (int j = 0; j < 16; ++j) {
      int pi = q + j*4;
      float s = lif_hard(tile[l][pi], v[j], 1.0f);
      xs[((size_t)(t*BB + b)*1024 + p0 + pi)*CC + c0 + l] = (f16)s;
    }
  }
}

// fragment read offset helper (row in [0,128), fq selects 16B k-slot; returns BYTES)
__device__ __forceinline__ int fragoff(int row, int fq) {
  return row*64 + ((fq*16) ^ (((row >> 1) & 3) << 4));
}

#define GLL(srcP, dstP) __builtin_amdgcn_global_load_lds( \
    (const __attribute__((address_space(1))) void*)(srcP), \
    (__attribute__((address_space(3))) void*)(dstP), 16, 0, 0)

// ---------- NP2 GEMM (gemm1/gemm3): hoisted pointers, 2 blocks/CU ----------
// NOTE: (256,3) spills the 128-VGPR accumulator (R18: VGPR 84, 711 MB scratch writes).
template<int GATE>
__global__ __launch_bounds__(256, 2) void k_gemmA(const f16* __restrict__ X1,
    const f16* __restrict__ Wa, const f16* __restrict__ Wb,
    const float* __restrict__ scale, const float* __restrict__ bias,
    float* __restrict__ out0, const f16* __restrict__ gatep) {
  __shared__ __align__(16) f16 lds[2*3*4096];       // 48 KB
  char* lbase = (char*)lds;
  const int gx = gridDim.x;
  const int bid = blockIdx.y * gx + blockIdx.x;
  const int chunk = (gx * gridDim.y) >> 3;
  const int nb = (bid & 7) * chunk + (bid >> 3);
  const int o0 = (nb % gx) * 128;
  const int m0 = (nb / gx) * 128;
  const int lane = threadIdx.x & 63, wid = threadIdx.x >> 6;
  const int wr = wid >> 1, wc = wid & 1;
  const int fr = lane & 15, fq = lane >> 4;
  f32x4 acc_h[4][4], acc_l[4][4];
  #pragma unroll
  for (int i = 0; i < 4; ++i)
    #pragma unroll
    for (int j = 0; j < 4; ++j) { acc_h[i][j] = (f32x4){0,0,0,0}; acc_l[i][j] = (f32x4){0,0,0,0}; }

  const f16* gp; int i0, nst, arr, row0;
  if (wid == 0)      { gp = X1; arr = 0; i0 = 0; nst = 4; row0 = m0; }
  else if (wid == 1) { gp = X1; arr = 0; i0 = 4; nst = 4; row0 = m0; }
  else if (wid == 2) { gp = Wa; arr = 1; i0 = 0; nst = 8; row0 = o0; }
  else               { gp = Wb; arr = 2; i0 = 0; nst = 8; row0 = o0; }
  const char* srcp[8]; int dsto[8];
  #pragma unroll
  for (int j = 0; j < 8; ++j) {
    int i = i0 + (j < nst ? j : 0);
    int loff = i*1024 + lane*16;
    int row = loff >> 6, col = loff & 63;
    int scol = col ^ (((row >> 1) & 3) << 4);
    srcp[j] = (const char*)gp + (size_t)(row0 + row)*768 + scol;
    dsto[j] = arr*8192 + i*1024;
  }
  int offA[4], offB1[4], offB2[4];
  #pragma unroll
  for (int mi = 0; mi < 4; ++mi) offA[mi] = fragoff(wr*64 + mi*16 + fr, fq);
  #pragma unroll
  for (int oi = 0; oi < 4; ++oi) {
    int o = fragoff(wc*64 + oi*16 + fr, fq);
    offB1[oi] = 8192 + o;
    offB2[oi] = 16384 + o;
  }

  const char* gb = nullptr; f16x8 gcur{}, gnxt{};
  if constexpr (GATE) {
    gb = (const char*)gatep + (size_t)(m0 >> 10)*768 + fq*16;
    gcur = *(const f16x8*)gb; gb += 64;
  }

#define ISSUE_A(BUF) { _Pragma("unroll") for (int j = 0; j < 8; ++j) if (j < nst) { \
    GLL(srcp[j], lbase + (BUF) + dsto[j]); srcp[j] += 64; } }
#define COMPUTE_A(BUF) { f16x8 a1[4], b1[4], b2[4]; \
    _Pragma("unroll") for (int mi = 0; mi < 4; ++mi) { \
      a1[mi] = *(const f16x8*)(lbase + (BUF) + offA[mi]); \
      if constexpr (GATE) a1[mi] = a1[mi] * gcur; } \
    _Pragma("unroll") for (int oi = 0; oi < 4; ++oi) { \
      b1[oi] = *(const f16x8*)(lbase + (BUF) + offB1[oi]); \
      b2[oi] = *(const f16x8*)(lbase + (BUF) + offB2[oi]); } \
    _Pragma("unroll") for (int mi = 0; mi < 4; ++mi) \
      _Pragma("unroll") for (int oi = 0; oi < 4; ++oi) { \
        acc_h[mi][oi] = __builtin_amdgcn_mfma_f32_16x16x32_f16(a1[mi], b1[oi], acc_h[mi][oi], 0, 0, 0); \
        acc_l[mi][oi] = __builtin_amdgcn_mfma_f32_16x16x32_f16(a1[mi], b2[oi], acc_l[mi][oi], 0, 0, 0); } }

  ISSUE_A(0);
  __syncthreads();
  #pragma unroll 1
  for (int it2 = 0; it2 < 6; ++it2) {
    ISSUE_A(24576);
    if constexpr (GATE) { gnxt = *(const f16x8*)gb; gb += 64; }
    COMPUTE_A(0);
    if constexpr (GATE) gcur = gnxt;
    __syncthreads();
    if (it2 < 5) {
      ISSUE_A(0);
      if constexpr (GATE) { gnxt = *(const f16x8*)gb; gb += 64; }
    }
    COMPUTE_A(24576);
    if constexpr (GATE) gcur = gnxt;
    __syncthreads();
  }
#undef ISSUE_A
#undef COMPUTE_A

  #pragma unroll
  for (int oi = 0; oi < 4; ++oi) {
    int o = o0 + wc*64 + oi*16 + fr;
    float sc = scale[o], bi = bias[o];
    #pragma unroll
    for (int mi = 0; mi < 4; ++mi) {
      f32x4 h = acc_h[mi][oi], lo2 = acc_l[mi][oi];
      #pragma unroll
      for (int r = 0; r < 4; ++r) {
        int m = m0 + wr*64 + mi*16 + fq*4 + r;
        float y = fmaf(0.00048828125f, lo2[r], h[r]);
        out0[(size_t)m*384 + o] = fmaf(y, sc, bi);
      }
    }
  }
}

// ---------- NP3 GEMM (qkv/proj): hoisted staging pointers, X2 LDS-staged ----------
// EPI=1: qkv fused LIF epilogue; EPI=2: proj fused output LIF, NCHW store.
template<int EPI>
__global__ __launch_bounds__(256, 2) void k_gemmB(const f16* __restrict__ X1, const f16* __restrict__ X2,
    const f16* __restrict__ Wa, const f16* __restrict__ Wb,
    const float* __restrict__ scale, const float* __restrict__ bias,
    float* __restrict__ outF, const float* __restrict__ gscale,
    f16* __restrict__ sOut, f16* __restrict__ part) {
  __shared__ __align__(16) f16 lds[2*4*4096];       // 64 KB (4 arrays x 8KB x 2 buf)
  char* lbase = (char*)lds;
  const int gx = gridDim.x;
  const int bid = blockIdx.y * gx + blockIdx.x;
  const int chunk = (gx * gridDim.y) >> 3;
  const int nb = (bid & 7) * chunk + (bid >> 3);
  const int o0 = (nb % gx) * 128;
  const int mb = nb / gx;
  const int b_ = mb >> 5, p0 = (mb & 31) << 5;      // t-grouped m-block decode
  const int lane = threadIdx.x & 63, wid = threadIdx.x >> 6;
  const int wr = wid >> 1, wc = wid & 1;
  const int fr = lane & 15, fq = lane >> 4;
  f32x4 acc_h[4][4], acc_l[4][4];
  #pragma unroll
  for (int i = 0; i < 4; ++i)
    #pragma unroll
    for (int j = 0; j < 4; ++j) { acc_h[i][j] = (f32x4){0,0,0,0}; acc_l[i][j] = (f32x4){0,0,0,0}; }

  // hoisted staging pointers: wave wid stages array wid (X1,X2,Wa,Wb), 8 insts each
  const f16* gp = (wid == 0) ? X1 : (wid == 1) ? X2 : (wid == 2) ? Wa : Wb;
  const bool isX = (wid <= 1);
  const char* srcp[8]; int dsto[8];
  #pragma unroll
  for (int i = 0; i < 8; ++i) {
    int loff = i*1024 + lane*16;              // BYTE offset within 8 KB tile
    int row = loff >> 6, col = loff & 63;
    int scol = col ^ (((row >> 1) & 3) << 4);
    int gm = isX ? (((row >> 5) << 14) + (b_ << 10) + p0 + (row & 31)) : (o0 + row);
    srcp[i] = (const char*)gp + (size_t)gm*768 + scol;
    dsto[i] = wid*8192 + i*1024;
  }
  int offA1[4], offA2[4], offB1[4], offB2[4];
  #pragma unroll
  for (int mi = 0; mi < 4; ++mi) {
    int o = fragoff(wr*64 + mi*16 + fr, fq);
    offA1[mi] = o;
    offA2[mi] = 8192 + o;
  }
  #pragma unroll
  for (int oi = 0; oi < 4; ++oi) {
    int o = fragoff(wc*64 + oi*16 + fr, fq);
    offB1[oi] = 16384 + o;
    offB2[oi] = 24576 + o;
  }

#define ISSUE_B(BUF) { _Pragma("unroll") for (int i = 0; i < 8; ++i) { \
    GLL(srcp[i], lbase + (BUF) + dsto[i]); srcp[i] += 64; } }
#define COMPUTE_B(BUF) { f16x8 a1[4], a2[4], b1[4], b2[4]; \
    _Pragma("unroll") for (int mi = 0; mi < 4; ++mi) { \
      a1[mi] = *(const f16x8*)(lbase + (BUF) + offA1[mi]); \
      a2[mi] = *(const f16x8*)(lbase + (BUF) + offA2[mi]); } \
    _Pragma("unroll") for (int oi = 0; oi < 4; ++oi) { \
      b1[oi] = *(const f16x8*)(lbase + (BUF) + offB1[oi]); \
      b2[oi] = *(const f16x8*)(lbase + (BUF) + offB2[oi]); } \
    _Pragma("unroll") for (int mi = 0; mi < 4; ++mi) \
      _Pragma("unroll") for (int oi = 0; oi < 4; ++oi) { \
        acc_h[mi][oi] = __builtin_amdgcn_mfma_f32_16x16x32_f16(a1[mi], b1[oi], acc_h[mi][oi], 0, 0, 0); \
        acc_l[mi][oi] = __builtin_amdgcn_mfma_f32_16x16x32_f16(a1[mi], b2[oi], acc_l[mi][oi], 0, 0, 0); \
        acc_l[mi][oi] = __builtin_amdgcn_mfma_f32_16x16x32_f16(a2[mi], b1[oi], acc_l[mi][oi], 0, 0, 0); } }

  ISSUE_B(0);
  __syncthreads();
  #pragma unroll 1
  for (int it2 = 0; it2 < 6; ++it2) {
    ISSUE_B(32768);
    COMPUTE_B(0);
    __syncthreads();
    if (it2 < 5) ISSUE_B(0);
    COMPUTE_B(32768);
    __syncthreads();
  }
#undef ISSUE_B
#undef COMPUTE_B

  // fused epilogue: BN -> in-LDS transpose (SWZ cols) -> LIF over t
  float* T = (float*)lds;
  #pragma unroll
  for (int oi = 0; oi < 4; ++oi) {
    int ol = wc*64 + oi*16 + fr;
    float sc = scale[o0 + ol], bi = bias[o0 + ol];
    #pragma unroll
    for (int mi = 0; mi < 4; ++mi) {
      f32x4 h = acc_h[mi][oi], lo2 = acc_l[mi][oi];
      #pragma unroll
      for (int r = 0; r < 4; ++r) {
        int R = wr*64 + mi*16 + fq*4 + r;
        float y = fmaf(0.00048828125f, lo2[r], h[r]);
        T[R*128 + (ol ^ SWZ(R))] = fmaf(y, sc, bi);
      }
    }
  }
  __syncthreads();
  const int tid = threadIdx.x;
  if constexpr (EPI == 1) {
    const int oc = tid & 127, ph = tid >> 7;
    if (o0 >= 384) {
      const int ocg = (o0 - 384) + oc;
      #pragma unroll
      for (int i = 0; i < 16; ++i) {
        int p = ph*16 + i;
        float v = 0.0f;
        #pragma unroll
        for (int t = 0; t < TT; ++t) {
          int R = t*32 + p;
          float s = lif_soft(T[R*128 + (oc ^ SWZ(R))], v);
          sOut[((size_t)((t*16 + b_)*1024 + p0 + p))*384 + ocg] = (f16)s;
        }
      }
    } else {
      float ps4[4] = {0,0,0,0};
      for (int i = 0; i < 16; ++i) {
        int p = ph*16 + i;
        float v = 0.0f;
        #pragma unroll
        for (int t = 0; t < TT; ++t) {
          int R = t*32 + p;
          ps4[t] += lif_soft(T[R*128 + (oc ^ SWZ(R))], v);
        }
      }
      int slice = (p0 >> 4) + ph;
      #pragma unroll
      for (int t = 0; t < TT; ++t)
        part[(((size_t)slice*4 + t)*16 + b_)*384 + o0 + oc] = (f16)ps4[t];
    }
  } else {
    const int p = tid & 31, cg = tid >> 5;
    const float gsc = gscale[0];
    #pragma unroll
    for (int j = 0; j < 16; ++j) {
      int c = cg*16 + j;
      float v = 0.0f;
      #pragma unroll
      for (int t = 0; t < TT; ++t) {
        int R = t*32 + p;
        float s = lif_soft(T[R*128 + (c ^ SWZ(R))], v) * gsc;
        outF[(((size_t)(t*16 + b_)*384) + o0 + c)*1024 + p0 + p] = s;
      }
    }
  }
}

// ---------- depthwise 3x3, NHWC, float4 channel-quads, fp32 in -> split-f16 out ----------
__global__ __launch_bounds__(256) void k_dw(const float* __restrict__ in, const float* __restrict__ wd,
                                            const float* __restrict__ pv,
                                            f16* __restrict__ outA, f16* __restrict__ outB) {
  const int ct = blockIdx.x, h = blockIdx.y, n = blockIdx.z;
  const int cq = threadIdx.x & 15, wg = threadIdx.x >> 4;
  const int c0 = ct*64 + cq*4;
  const int w0 = wg*2;
  float w9[9][4];
  #pragma unroll
  for (int j = 0; j < 4; ++j)
    #pragma unroll
    for (int k = 0; k < 9; ++k) w9[k][j] = wd[(c0 + j)*9 + k];
  const float4 pv4 = *(const float4*)&pv[c0];
  const float* base = in + (size_t)n*1024*CC;
  float4 col[3][4];
  #pragma unroll
  for (int r = 0; r < 3; ++r)
    #pragma unroll
    for (int j = 0; j < 4; ++j) {
      int hh = h - 1 + r, ww = w0 - 1 + j;
      col[r][j] = ((unsigned)hh < 32u && (unsigned)ww < 32u)
                  ? *(const float4*)&base[(size_t)(hh*32 + ww)*CC + c0] : pv4;
    }
  #pragma unroll
  for (int wi = 0; wi < 2; ++wi) {
    float acc[4] = {0.f, 0.f, 0.f, 0.f};
    #pragma unroll
    for (int dh = 0; dh < 3; ++dh)
      #pragma unroll
      for (int dwj = 0; dwj < 3; ++dwj) {
        float4 vv = col[dh][wi + dwj];
        const float* wk = w9[dh*3 + dwj];
        acc[0] = fmaf(wk[0], vv.x, acc[0]);
        acc[1] = fmaf(wk[1], vv.y, acc[1]);
        acc[2] = fmaf(wk[2], vv.z, acc[2]);
        acc[3] = fmaf(wk[3], vv.w, acc[3]);
      }
    f16x4 a4, b4;
    #pragma unroll
    for (int j = 0; j < 4; ++j) {
      f16 a = (f16)acc[j];
      a4[j] = a;
      b4[j] = (f16)((acc[j] - (float)a) * 2048.0f);
    }
    size_t off = ((size_t)n*1024 + h*32 + w0 + wi)*CC + c0;
    *(f16x4*)&outA[off] = a4;
    *(f16x4*)&outB[off] = b4;
  }
}

// ---------- gate: combine 64 partial half-slices + LIF(hard 0.5) -> f16 gate ----------
__global__ __launch_bounds__(256) void k_gate(const f16* __restrict__ partial, f16* __restrict__ gate16) {
  int g = blockIdx.x*256 + threadIdx.x;   // 6144 = 16*384
  int b = g / CC, c = g % CC;
  float sums[4];
  #pragma unroll
  for (int t = 0; t < TT; ++t) {
    float s = 0.0f;
    for (int ps = 0; ps < 64; ++ps) s += (float)partial[(((size_t)ps*4 + t)*BB + b)*CC + c];
    sums[t] = s;
  }
  float v = 0.0f;
  #pragma unroll
  for (int t = 0; t < TT; ++t)
    gate16[((size_t)(t*BB + b))*CC + c] = (f16)lif_hard(sums[t], v, 0.5f);
}

extern "C" void kernel_launch(void* const* d_in, const int* in_sizes, int n_in,
                              void* d_out, int out_size, void* d_ws, size_t ws_size,
                              hipStream_t stream) {
  const float* x      = (const float*)d_in[0];
  const float* r1_w1  = (const float*)d_in[1];
  const float* r1_bn1 = (const float*)d_in[2];
  const float* r1_dw  = (const float*)d_in[3];
  const float* r1_pw  = (const float*)d_in[4];
  const float* r1_bn2 = (const float*)d_in[5];
  const float* qkv_bn = (const float*)d_in[6];
  const float* r2_w1  = (const float*)d_in[7];
  const float* r2_bn1 = (const float*)d_in[8];
  const float* r2_dw  = (const float*)d_in[9];
  const float* r2_pw  = (const float*)d_in[10];
  const float* r2_bn2 = (const float*)d_in[11];
  const float* proj_bn= (const float*)d_in[12];
  const float* scale  = (const float*)d_in[13];

  float* ws = (float*)d_ws;
  const size_t SEG = 12582912;              // 50.3 MB in floats
  float* W0f = ws;                          // f16 region: xs -> s16
  float* W1  = ws + SEG;                    // fp32: t1 -> t2
  float* W2f = ws + 3*SEG;                  // f16 region: p1a -> p2a
  float* W3f = ws + 4*SEG;                  // f16 region: p1b -> p2b
  f16* xs  = (f16*)W0f;
  f16* s16 = (f16*)W0f;
  float* t1 = W1;
  float* t2 = W1;
  f16* p1a = (f16*)W2f;
  f16* p2a = (f16*)W2f;
  f16* p1b = (f16*)W3f;
  f16* p2b = (f16*)W3f;

  f16* wsp = (f16*)(ws + 6*SEG);            // param region
  f16* w1a = wsp,              *w1b = wsp + 147456;
  f16* pwa = wsp + 294912,     *pwb = wsp + 589824;
  f16* q1a = wsp + 884736,     *q1b = wsp + 1032192;
  f16* qpa = wsp + 1179648,    *qpb = wsp + 1327104;
  f16* partial = wsp + 1474560;             // 64*4*16*384 f16
  f16* gate16  = wsp + 3047424;             // 64*384 f16
  float* par = (float*)(wsp + 3072000);     // 3840 floats
  float* s1 = par,        *o1 = par + 384;
  float* sA = par + 768,  *oA = par + 1536;
  float* s2 = par + 2304, *o2 = par + 2688;
  float* sB = par + 3072, *oB = par + 3456;

  k_prep_all<<<2883, 256, 0, stream>>>(r1_w1, r1_pw, r2_w1, r2_pw,
                                       w1a, w1b, pwa, pwb, q1a, q1b, qpa, qpb,
                                       r1_bn1, r1_bn2, qkv_bn, r2_bn1, r2_bn2, proj_bn, par);
  k_lif_in<<<dim3(16, 6, 16), 256, 0, stream>>>(x, xs);
  // repconv1
  k_gemmA<0><<<dim3(3, 512), 256, 0, stream>>>(xs, w1a, w1b, s1, o1, t1, nullptr);
  k_dw<<<dim3(6, 32, 64), 256, 0, stream>>>(t1, r1_dw, o1, p1a, p1b);
  // qkv GEMM with fused LIF epilogue: qk -> partial sums, v -> spikes
  k_gemmB<1><<<dim3(6, 512), 256, 0, stream>>>(p1a, p1b, pwa, pwb, sA, oA,
                                               nullptr, nullptr, s16, partial);
  k_gate<<<24, 256, 0, stream>>>(partial, gate16);
  // repconv2 (gate applied inline on A-frags)
  k_gemmA<1><<<dim3(3, 512), 256, 0, stream>>>(s16, q1a, q1b, s2, o2, t2, gate16);
  k_dw<<<dim3(6, 32, 64), 256, 0, stream>>>(t2, r2_dw, o2, p2a, p2b);
  // proj GEMM with fused output LIF, direct NCHW write
  k_gemmB<2><<<dim3(3, 512), 256, 0, stream>>>(p2a, p2b, qpa, qpb, sB, oB,
                                               (float*)d_out, scale, nullptr, nullptr);
}